// Round 12
// baseline (104.733 us; speedup 1.0000x reference)
//
#include <hip/hip_runtime.h>
#include <math.h>

#define B 4
#define C 128
#define CPG 16
#define INTER 32
#define KS 4

#define N1 4096
#define N2 1024
#define N4 256

// element offsets (compile-time)
#define QOFF2 (B * N1 * 32)                  // 524288
#define QOFF4 (QOFF2 + B * N2 * 32)          // 655360
#define QTOT  (QOFF4 + B * N4 * 32)          // 688128
#define PAOFF2 (B * KS * 32 * N1)            // 2097152
#define PAOFF4 (PAOFF2 + B * KS * 32 * N2)   // 2621440
#define PATOT  (PAOFF4 + B * KS * 32 * N4)   // 2752512
#define PMOFF2 (B * KS * 2 * N1)             // 131072
#define PMOFF4 (PMOFF2 + B * KS * 2 * N2)    // 163840
#define PMTOT  (PMOFF4 + B * KS * 2 * N4)    // 172032

// (1/sqrt(32)) * log2(e), folded into Q at projection time
#define QSCALE 0.25503490f

typedef unsigned short ushort_t;
typedef __attribute__((ext_vector_type(8))) short short8;
typedef __attribute__((ext_vector_type(4))) float f32x4;

__device__ __forceinline__ ushort_t f2bf(float f) {
    union { float f; unsigned u; } x; x.f = f;
    unsigned r = x.u + 0x7fffu + ((x.u >> 16) & 1u);
    return (ushort_t)(r >> 16);
}

__device__ __forceinline__ void scale_wts(const float* __restrict__ sw,
                                          float& w0, float& w1, float& w2) {
    float a = sw[0], b = sw[1], c = sw[2];
    float m = fmaxf(a, fmaxf(b, c));
    float e0 = __expf(a - m), e1 = __expf(b - m), e2 = __expf(c - m);
    float inv = 1.0f / (e0 + e1 + e2);
    w0 = e0 * inv; w1 = e1 * inv; w2 = e2 * inv;
}

// safe for multiple sequential calls in one kernel (leading sync protects reuse)
__device__ __forceinline__ void block_reduce_write(float s, float q,
                                                   float* __restrict__ dst2) {
    __shared__ float rs[256], rq[256];
    __syncthreads();
    rs[threadIdx.x] = s; rq[threadIdx.x] = q;
    __syncthreads();
    for (int st = 128; st > 0; st >>= 1) {
        if (threadIdx.x < st) {
            rs[threadIdx.x] += rs[threadIdx.x + st];
            rq[threadIdx.x] += rq[threadIdx.x + st];
        }
        __syncthreads();
    }
    if (threadIdx.x == 0) { dst2[0] = rs[0]; dst2[1] = rq[0]; }
}

// ---------- kernel 1: one block per (b,c) plane: s1 stats + s2/s4 pool+stats ----------
// part layout: [bc][6] = {s1 sum, s1 sq, s2 sum, s2 sq, s4 sum, s4 sq}
__global__ __launch_bounds__(256) void pool_stats_kernel(const float* __restrict__ x,
                                                         float* __restrict__ xs2,
                                                         float* __restrict__ xs4,
                                                         float* __restrict__ part) {
    int bc = blockIdx.x;                  // 0..511
    const float* src = x + ((size_t)bc << 12);
    int t = threadIdx.x;
    // s=1 stats (streams plane through L1)
    float s1 = 0.0f, q1 = 0.0f;
    for (int i = t; i < 4096; i += 256) {
        float v = src[i];
        s1 += v; q1 += v * v;
    }
    // s=2 pool + stats (re-reads from L1)
    float* dst2 = xs2 + ((size_t)bc << 10);
    float s2 = 0.0f, q2 = 0.0f;
    for (int p = t; p < 1024; p += 256) {
        int oy = p >> 5, ox = p & 31;
        const float* sp = src + oy * 128 + ox * 2;
        float v = (sp[0] + sp[1] + sp[64] + sp[65]) * 0.25f;
        dst2[p] = v; s2 += v; q2 += v * v;
    }
    // s=4 pool + stats (1 px/thread)
    float* dst4 = xs4 + ((size_t)bc << 8);
    float s4 = 0.0f, q4 = 0.0f;
    {
        int oy = t >> 4, ox = t & 15;
        const float* sp = src + oy * 256 + ox * 4;
        float v = 0.0f;
        #pragma unroll
        for (int dy = 0; dy < 4; ++dy)
            #pragma unroll
            for (int dx = 0; dx < 4; ++dx) v += sp[dy * 64 + dx];
        v *= 0.0625f;
        dst4[t] = v; s4 = v; q4 = v * v;
    }
    block_reduce_write(s1, q1, part + bc * 6);
    block_reduce_write(s2, q2, part + bc * 6 + 2);
    block_reduce_write(s4, q4, part + bc * 6 + 4);
}

// ---------- kernel 2: QKV projection, 32 outputs/block, inline GN fold ----------
template <int N, int NSH, int SLOT>
__device__ __forceinline__ void qkv_body(int proj, int b, int nchunk,
    const float* __restrict__ xs, const float* __restrict__ part,
    const float* __restrict__ gn_w, const float* __restrict__ gn_b,
    const float* __restrict__ wp, const float* __restrict__ bp,
    ushort_t* __restrict__ q_bf, ushort_t* __restrict__ k_bf, ushort_t* __restrict__ v_bf) {
    __shared__ float wl[128 * 32];        // [c][o], 16 KB
    __shared__ float2 ss[128];
    int t = threadIdx.x;
    #pragma unroll
    for (int r = 0; r < 16; ++r) {
        int e = r * 256 + t;              // e = c*32 + o
        int c0 = e >> 5, o = e & 31;
        wl[e] = wp[o * C + c0];
    }
    if (t < 128) {
        int c = t;
        int gbase = b * C + ((c >> 4) << 4);
        float s = 0.0f, q = 0.0f;
        #pragma unroll
        for (int j = 0; j < 16; ++j) {
            s += part[(gbase + j) * 6 + SLOT * 2];
            q += part[(gbase + j) * 6 + SLOT * 2 + 1];
        }
        float inv = 1.0f / (float)(CPG << NSH);
        float mu = s * inv;
        float var = q * inv - mu * mu;
        float a = rsqrtf(var + 1e-5f) * gn_w[c];
        float2 r; r.x = a; r.y = gn_b[c] - mu * a;
        ss[c] = r;
    }
    __syncthreads();
    int n = nchunk * 256 + t;
    const float* xb = xs + ((size_t)(b * C) << NSH) + n;
    float acc[32];
    #pragma unroll
    for (int o = 0; o < 32; ++o) acc[o] = bp[o];
    #pragma unroll 2
    for (int c0 = 0; c0 < C; ++c0) {
        float2 s2 = ss[c0];
        float xv = fmaf(s2.x, xb[(size_t)c0 << NSH], s2.y);
        const float4* wr = (const float4*)&wl[c0 * 32];
        #pragma unroll
        for (int i4 = 0; i4 < 8; ++i4) {
            float4 wv = wr[i4];
            acc[i4 * 4 + 0] += wv.x * xv; acc[i4 * 4 + 1] += wv.y * xv;
            acc[i4 * 4 + 2] += wv.z * xv; acc[i4 * 4 + 3] += wv.w * xv;
        }
    }
    if (proj < 2) {
        float fs = (proj == 0) ? QSCALE : 1.0f;
        ushort_t tmp[32];
        #pragma unroll
        for (int o = 0; o < 32; ++o) tmp[o] = f2bf(acc[o] * fs);
        ushort_t* dst = ((proj == 0) ? q_bf : k_bf) + (size_t)(b * N + n) * 32;
        const uint4* tv = (const uint4*)tmp;
        ((uint4*)dst)[0] = tv[0]; ((uint4*)dst)[1] = tv[1];
        ((uint4*)dst)[2] = tv[2]; ((uint4*)dst)[3] = tv[3];
    } else {
        #pragma unroll
        for (int o = 0; o < 32; ++o)
            v_bf[((size_t)(b * 32 + o) << NSH) + n] = f2bf(acc[o]);
    }
}

__global__ __launch_bounds__(256) void qkv_all_kernel(const float* __restrict__ x,
    const float* __restrict__ xs2, const float* __restrict__ xs4,
    const float* __restrict__ part,
    const float* __restrict__ gn_w, const float* __restrict__ gn_b,
    const float* __restrict__ qw, const float* __restrict__ qb,
    const float* __restrict__ kw, const float* __restrict__ kb,
    const float* __restrict__ vw, const float* __restrict__ vb,
    ushort_t* __restrict__ qbf, ushort_t* __restrict__ kbf, ushort_t* __restrict__ vbf) {
    int bid = blockIdx.x;
    if (bid < 192) {              // s=1: 3 proj x 4 b x 16 chunks
        int proj = bid / 64, r = bid % 64, b_ = r >> 4, nch = r & 15;
        const float* wp = (proj == 0) ? qw : ((proj == 1) ? kw : vw);
        const float* bp = (proj == 0) ? qb : ((proj == 1) ? kb : vb);
        qkv_body<N1, 12, 0>(proj, b_, nch, x, part, gn_w, gn_b, wp, bp, qbf, kbf, vbf);
    } else if (bid < 240) {       // s=2: 3 x 4 x 4
        int u = bid - 192;
        int proj = u / 16, r = u % 16, b_ = r >> 2, nch = r & 3;
        const float* wp = ((proj == 0) ? qw : ((proj == 1) ? kw : vw)) + INTER * C;
        const float* bp = ((proj == 0) ? qb : ((proj == 1) ? kb : vb)) + INTER;
        qkv_body<N2, 10, 1>(proj, b_, nch, xs2, part, gn_w + C, gn_b + C, wp, bp,
                            qbf + QOFF2, kbf + QOFF2, vbf + QOFF2);
    } else {                      // s=4: 3 x 4 x 1
        int u = bid - 240;
        int proj = u / 4, b_ = u % 4;
        const float* wp = ((proj == 0) ? qw : ((proj == 1) ? kw : vw)) + 2 * INTER * C;
        const float* bp = ((proj == 0) ? qb : ((proj == 1) ? kb : vb)) + 2 * INTER;
        qkv_body<N4, 8, 2>(proj, b_, 0, xs4, part, gn_w + 2 * C, gn_b + 2 * C, wp, bp,
                           qbf + QOFF4, kbf + QOFF4, vbf + QOFF4);
    }
}

// ---------- softmax + P-pack for one fragment (defer-max, exp2 domain) ----------
#define SOFTMAX_PACK(sa, mrun, lrun, aA, aB, PwF)                                              \
    {                                                                                          \
        float s_[16];                                                                          \
        _Pragma("unroll")                                                                      \
        for (int kt = 0; kt < 4; ++kt) {                                                       \
            s_[kt * 4 + 0] = sa[kt][0]; s_[kt * 4 + 1] = sa[kt][1];                            \
            s_[kt * 4 + 2] = sa[kt][2]; s_[kt * 4 + 3] = sa[kt][3];                            \
        }                                                                                      \
        float t0 = fmaxf(fmaxf(s_[0], s_[1]), s_[2]);                                          \
        float t1 = fmaxf(fmaxf(s_[3], s_[4]), s_[5]);                                          \
        float t2 = fmaxf(fmaxf(s_[6], s_[7]), s_[8]);                                          \
        float t3 = fmaxf(fmaxf(s_[9], s_[10]), s_[11]);                                        \
        float t4 = fmaxf(fmaxf(s_[12], s_[13]), s_[14]);                                       \
        float tmax = fmaxf(fmaxf(fmaxf(t0, t1), fmaxf(t2, t3)), fmaxf(t4, s_[15]));            \
        tmax = fmaxf(tmax, __shfl_xor(tmax, 16, 64));                                          \
        tmax = fmaxf(tmax, __shfl_xor(tmax, 32, 64));                                          \
        if (!__all(tmax - mrun <= 8.0f)) {                                                     \
            float nmx = fmaxf(mrun, tmax);                                                     \
            float corr = exp2f(mrun - nmx);                                                    \
            lrun *= corr;                                                                      \
            _Pragma("unroll")                                                                  \
            for (int e = 0; e < 4; ++e) { aA[e] *= corr; aB[e] *= corr; }                       \
            mrun = nmx;                                                                        \
        }                                                                                      \
        float p_[16];                                                                          \
        float psum = 0.0f;                                                                     \
        _Pragma("unroll")                                                                      \
        for (int j = 0; j < 16; ++j) { p_[j] = exp2f(s_[j] - mrun); psum += p_[j]; }           \
        psum += __shfl_xor(psum, 16, 64);                                                      \
        psum += __shfl_xor(psum, 32, 64);                                                      \
        lrun += psum;                                                                          \
        _Pragma("unroll")                                                                      \
        for (int kt = 0; kt < 4; ++kt) {                                                       \
            unsigned u01, u23;                                                                 \
            asm("v_cvt_pk_bf16_f32 %0, %1, %2" : "=v"(u01) : "v"(p_[kt * 4 + 0]), "v"(p_[kt * 4 + 1])); \
            asm("v_cvt_pk_bf16_f32 %0, %1, %2" : "=v"(u23) : "v"(p_[kt * 4 + 2]), "v"(p_[kt * 4 + 3])); \
            uint2 pv; pv.x = u01; pv.y = u23;                                                  \
            *(uint2*)&(PwF)[lq * 64 + (((kt * 32 + g * 8) ^ ((lq & 7) << 4)) >> 1)] = pv;      \
        }                                                                                      \
    }

// ---------- kernel 3: MFMA flash attention, 2 Q-fragments/wave, KS=4 ----------
template <int N, int NSH>
__device__ __forceinline__ void attn_body(int bi,
    const ushort_t* __restrict__ q_bf, const ushort_t* __restrict__ k_bf,
    const ushort_t* __restrict__ v_bf,
    float* __restrict__ pacc, float* __restrict__ pml,
    ushort_t* K_lds, ushort_t* V_lds, ushort_t* P_lds) {
    int ks = bi % KS; bi /= KS;
    const int nqc = N >> 7;
    int qc = bi % nqc; int b = bi / nqc;
    int tid = threadIdx.x;
    int l = tid & 63, w = tid >> 6, lq = l & 15, g = l >> 4;
    int q0 = qc * 128 + w * 32;

    short8 qf0 = *(const short8*)(q_bf + ((size_t)(b * N + q0 + lq)) * 32 + g * 8);
    short8 qf1 = *(const short8*)(q_bf + ((size_t)(b * N + q0 + 16 + lq)) * 32 + g * 8);
    f32x4 a00 = {0.f, 0.f, 0.f, 0.f}, a01 = {0.f, 0.f, 0.f, 0.f};
    f32x4 a10 = {0.f, 0.f, 0.f, 0.f}, a11 = {0.f, 0.f, 0.f, 0.f};
    float m0 = -3.0e38f, l0 = 0.0f, m1 = -3.0e38f, l1 = 0.0f;

    const int kchunk = N / KS;
    int kbase = ks * kchunk;
    const int ntiles = kchunk >> 6;
    ushort_t* Pw = P_lds + w * (32 * 64);

    const int krow = tid >> 2;
    const int kidx = krow * 32 + ((((tid & 3) * 16) ^ ((krow & 3) << 4)) >> 1);
    const int vrow = tid >> 3;
    const int vidx = vrow * 64 + ((((tid & 7) * 16) ^ ((vrow & 7) << 4)) >> 1);

    const uint4* ksrc = (const uint4*)(k_bf + ((size_t)(b * N + kbase + krow)) * 32 + (tid & 3) * 8);
    const uint4* vsrc = (const uint4*)(v_bf + (((size_t)(b * 32 + vrow)) << NSH) + kbase + (tid & 7) * 8);
    uint4 kreg = *ksrc, vreg = *vsrc;

    const int ksw = (g ^ (lq & 3)) << 3;
    const int vsw0 = ((g * 16) ^ ((lq & 7) << 4)) >> 1;
    const int vsw1 = ((64 + g * 16) ^ ((lq & 7) << 4)) >> 1;

    for (int t = 0; t < ntiles; ++t) {
        __syncthreads();
        *(uint4*)&K_lds[kidx] = kreg;
        *(uint4*)&V_lds[vidx] = vreg;
        __syncthreads();
        if (t + 1 < ntiles) {                 // prefetch next tile under compute
            ksrc += 256; vsrc += 8;
            kreg = *ksrc; vreg = *vsrc;
        }

        f32x4 sa0[4], sa1[4];
        #pragma unroll
        for (int kt = 0; kt < 4; ++kt) {
            short8 kf = *(const short8*)&K_lds[(kt * 16 + lq) * 32 + ksw];
            f32x4 z = {0.f, 0.f, 0.f, 0.f};
            sa0[kt] = __builtin_amdgcn_mfma_f32_16x16x32_bf16(kf, qf0, z, 0, 0, 0);
            sa1[kt] = __builtin_amdgcn_mfma_f32_16x16x32_bf16(kf, qf1, z, 0, 0, 0);
        }
        SOFTMAX_PACK(sa0, m0, l0, a00, a01, Pw)
        SOFTMAX_PACK(sa1, m1, l1, a10, a11, (Pw + 16 * 64))

        short8 vf00 = *(const short8*)&V_lds[lq * 64 + vsw0];
        short8 vf10 = *(const short8*)&V_lds[(16 + lq) * 64 + vsw0];
        short8 vf01 = *(const short8*)&V_lds[lq * 64 + vsw1];
        short8 vf11 = *(const short8*)&V_lds[(16 + lq) * 64 + vsw1];
        short8 p00 = *(const short8*)&Pw[lq * 64 + vsw0];
        short8 p01 = *(const short8*)&Pw[lq * 64 + vsw1];
        short8 p10 = *(const short8*)&Pw[(16 + lq) * 64 + vsw0];
        short8 p11 = *(const short8*)&Pw[(16 + lq) * 64 + vsw1];
        a00 = __builtin_amdgcn_mfma_f32_16x16x32_bf16(vf00, p00, a00, 0, 0, 0);
        a01 = __builtin_amdgcn_mfma_f32_16x16x32_bf16(vf10, p00, a01, 0, 0, 0);
        a00 = __builtin_amdgcn_mfma_f32_16x16x32_bf16(vf01, p01, a00, 0, 0, 0);
        a01 = __builtin_amdgcn_mfma_f32_16x16x32_bf16(vf11, p01, a01, 0, 0, 0);
        a10 = __builtin_amdgcn_mfma_f32_16x16x32_bf16(vf00, p10, a10, 0, 0, 0);
        a11 = __builtin_amdgcn_mfma_f32_16x16x32_bf16(vf10, p10, a11, 0, 0, 0);
        a10 = __builtin_amdgcn_mfma_f32_16x16x32_bf16(vf01, p11, a10, 0, 0, 0);
        a11 = __builtin_amdgcn_mfma_f32_16x16x32_bf16(vf11, p11, a11, 0, 0, 0);
    }
    int n0 = q0 + lq, n1 = q0 + 16 + lq;
    size_t pb_ = ((size_t)(b * KS + ks)) * 32;
    #pragma unroll
    for (int r = 0; r < 4; ++r) {
        pacc[(pb_ + (g * 4 + r)) * N + n0]      = a00[r];
        pacc[(pb_ + 16 + (g * 4 + r)) * N + n0] = a01[r];
        pacc[(pb_ + (g * 4 + r)) * N + n1]      = a10[r];
        pacc[(pb_ + 16 + (g * 4 + r)) * N + n1] = a11[r];
    }
    if (g == 0) {
        pml[((size_t)(b * KS + ks) * 2) * N + n0]     = m0;
        pml[((size_t)(b * KS + ks) * 2 + 1) * N + n0] = l0;
        pml[((size_t)(b * KS + ks) * 2) * N + n1]     = m1;
        pml[((size_t)(b * KS + ks) * 2 + 1) * N + n1] = l1;
    }
}

__global__ __launch_bounds__(256) void attn_all_kernel(
    const ushort_t* __restrict__ qbf, const ushort_t* __restrict__ kbf,
    const ushort_t* __restrict__ vbf,
    float* __restrict__ pacc, float* __restrict__ pml) {
    __shared__ ushort_t K_lds[64 * 32];        // 4 KB
    __shared__ ushort_t V_lds[32 * 64];        // 4 KB
    __shared__ ushort_t P_lds[4 * 32 * 64];    // 16 KB
    int bid = blockIdx.x;
    if (bid < 512) {
        attn_body<N1, 12>(bid, qbf, kbf, vbf, pacc, pml, K_lds, V_lds, P_lds);
    } else if (bid < 640) {
        attn_body<N2, 10>(bid - 512, qbf + QOFF2, kbf + QOFF2, vbf + QOFF2,
                          pacc + PAOFF2, pml + PMOFF2, K_lds, V_lds, P_lds);
    } else {
        attn_body<N4, 8>(bid - 640, qbf + QOFF4, kbf + QOFF4, vbf + QOFF4,
                         pacc + PAOFF4, pml + PMOFF4, K_lds, V_lds, P_lds);
    }
}

// ---------- kernel 4: combine + oy + residual for s=2/s=4 ----------
template <int N, int NSH>
__device__ __forceinline__ void comb_oy_body(int tile, const float* __restrict__ pacc,
    const float* __restrict__ pml, const float* __restrict__ ow, const float* __restrict__ ob,
    const float* __restrict__ gamma, const float* __restrict__ xs,
    float* __restrict__ ydst, float* att_lds, float* ow_lds) {
    const int ntiles = N >> 5;
    int b = tile / ntiles;
    int n0 = (tile % ntiles) << 5;
    int t = threadIdx.x;
    {
        const float4* src = (const float4*)ow;
        float4* dst = (float4*)ow_lds;
        dst[t] = src[t]; dst[256 + t] = src[256 + t];
        dst[512 + t] = src[512 + t]; dst[768 + t] = src[768 + t];
    }
    {
        int o = t >> 3, j = t & 7;
        int n = n0 + j * 4;
        float4 mv[KS];
        float4 M = {-3.0e38f, -3.0e38f, -3.0e38f, -3.0e38f};
        #pragma unroll
        for (int k2 = 0; k2 < KS; ++k2) {
            mv[k2] = *(const float4*)&pml[((size_t)(b * KS + k2) * 2) * N + n];
            M.x = fmaxf(M.x, mv[k2].x); M.y = fmaxf(M.y, mv[k2].y);
            M.z = fmaxf(M.z, mv[k2].z); M.w = fmaxf(M.w, mv[k2].w);
        }
        float4 L = {0.f, 0.f, 0.f, 0.f}, A = {0.f, 0.f, 0.f, 0.f};
        #pragma unroll
        for (int k2 = 0; k2 < KS; ++k2) {
            float4 lv = *(const float4*)&pml[((size_t)(b * KS + k2) * 2 + 1) * N + n];
            float4 av = *(const float4*)&pacc[((size_t)(b * KS + k2) * INTER + o) * N + n];
            float4 wg;                         // log2-domain m -> exp2
            wg.x = exp2f(mv[k2].x - M.x); wg.y = exp2f(mv[k2].y - M.y);
            wg.z = exp2f(mv[k2].z - M.z); wg.w = exp2f(mv[k2].w - M.w);
            L.x += lv.x * wg.x; L.y += lv.y * wg.y;
            L.z += lv.z * wg.z; L.w += lv.w * wg.w;
            A.x += av.x * wg.x; A.y += av.y * wg.y;
            A.z += av.z * wg.z; A.w += av.w * wg.w;
        }
        float4 r;
        r.x = A.x / L.x; r.y = A.y / L.y; r.z = A.z / L.z; r.w = A.w / L.w;
        *(float4*)&att_lds[o * 36 + j * 4] = r;
    }
    __syncthreads();
    {
        int n = t & 31, cg2 = t >> 5;
        float av[32];
        #pragma unroll
        for (int i = 0; i < 32; ++i) av[i] = att_lds[i * 36 + n];
        float gm = gamma[0];
        const float* xsb = xs + ((size_t)(b * C + cg2 * 16) << NSH) + n0 + n;
        float* yb = ydst + ((size_t)(b * C + cg2 * 16) << NSH) + n0 + n;
        #pragma unroll 4
        for (int cc = 0; cc < 16; ++cc) {
            int c = cg2 * 16 + cc;
            const float4* wr = (const float4*)&ow_lds[c * 32];
            float a0 = 0.f, a1 = 0.f, a2 = 0.f, a3 = 0.f;
            #pragma unroll
            for (int i4 = 0; i4 < 8; ++i4) {
                float4 wv = wr[i4];
                a0 += wv.x * av[i4 * 4 + 0]; a1 += wv.y * av[i4 * 4 + 1];
                a2 += wv.z * av[i4 * 4 + 2]; a3 += wv.w * av[i4 * 4 + 3];
            }
            float o_ = ob[c] + ((a0 + a1) + (a2 + a3));
            yb[(size_t)cc << NSH] = gm * o_ + xsb[(size_t)cc << NSH];
        }
    }
}

__global__ __launch_bounds__(256) void comb_s24_kernel(const float* __restrict__ pacc,
    const float* __restrict__ pml,
    const float* __restrict__ ow, const float* __restrict__ ob,
    const float* __restrict__ gamma,
    const float* __restrict__ xs2, const float* __restrict__ xs4,
    float* __restrict__ y2, float* __restrict__ y4) {
    __shared__ float att_lds[32 * 36];
    __shared__ float ow_lds[128 * 32];
    int bid = blockIdx.x;
    if (bid < 128) {
        comb_oy_body<N2, 10>(bid, pacc + PAOFF2, pml + PMOFF2,
                             ow + C * INTER, ob + C, gamma + 1, xs2, y2, att_lds, ow_lds);
    } else {
        comb_oy_body<N4, 8>(bid - 128, pacc + PAOFF4, pml + PMOFF4,
                            ow + 2 * C * INTER, ob + 2 * C, gamma + 2, xs4, y4,
                            att_lds, ow_lds);
    }
}

// ---------- kernel 5: s=1 combine + oy + residual + bilinear fuse ----------
__global__ __launch_bounds__(256) void comb_oy_s1_fuse_kernel(
    const float* __restrict__ pacc, const float* __restrict__ pml,
    const float* __restrict__ ow, const float* __restrict__ ob,
    const float* __restrict__ gamma, const float* __restrict__ x,
    const float* __restrict__ y2, const float* __restrict__ y4,
    float* __restrict__ out, const float* __restrict__ sw) {
    __shared__ float att_lds[32 * 36];
    __shared__ float ow_lds[128 * 32];
    const int N = N1;
    int tile = blockIdx.x;
    int b = tile >> 7;
    int n0 = (tile & 127) << 5;
    int t = threadIdx.x;
    {
        const float4* src = (const float4*)ow;
        float4* dst = (float4*)ow_lds;
        dst[t] = src[t]; dst[256 + t] = src[256 + t];
        dst[512 + t] = src[512 + t]; dst[768 + t] = src[768 + t];
    }
    {
        int o = t >> 3, j = t & 7;
        int n = n0 + j * 4;
        float4 mv[KS];
        float4 M = {-3.0e38f, -3.0e38f, -3.0e38f, -3.0e38f};
        #pragma unroll
        for (int k2 = 0; k2 < KS; ++k2) {
            mv[k2] = *(const float4*)&pml[((size_t)(b * KS + k2) * 2) * N + n];
            M.x = fmaxf(M.x, mv[k2].x); M.y = fmaxf(M.y, mv[k2].y);
            M.z = fmaxf(M.z, mv[k2].z); M.w = fmaxf(M.w, mv[k2].w);
        }
        float4 L = {0.f, 0.f, 0.f, 0.f}, A = {0.f, 0.f, 0.f, 0.f};
        #pragma unroll
        for (int k2 = 0; k2 < KS; ++k2) {
            float4 lv = *(const float4*)&pml[((size_t)(b * KS + k2) * 2 + 1) * N + n];
            float4 av = *(const float4*)&pacc[((size_t)(b * KS + k2) * INTER + o) * N + n];
            float4 wg;                          // log2-domain m -> exp2
            wg.x = exp2f(mv[k2].x - M.x); wg.y = exp2f(mv[k2].y - M.y);
            wg.z = exp2f(mv[k2].z - M.z); wg.w = exp2f(mv[k2].w - M.w);
            L.x += lv.x * wg.x; L.y += lv.y * wg.y;
            L.z += lv.z * wg.z; L.w += lv.w * wg.w;
            A.x += av.x * wg.x; A.y += av.y * wg.y;
            A.z += av.z * wg.z; A.w += av.w * wg.w;
        }
        float4 r;
        r.x = A.x / L.x; r.y = A.y / L.y; r.z = A.z / L.z; r.w = A.w / L.w;
        *(float4*)&att_lds[o * 36 + j * 4] = r;
    }
    __syncthreads();
    {
        int n = t & 31, cg2 = t >> 5;
        float av[32];
        #pragma unroll
        for (int i = 0; i < 32; ++i) av[i] = att_lds[i * 36 + n];
        float gm = gamma[0];
        float w0, w1, w2; scale_wts(sw, w0, w1, w2);
        int p = n0 + n, oy = p >> 6, ox = p & 63;
        float cy2 = fminf(fmaxf((oy + 0.5f) * 0.5f - 0.5f, 0.0f), 31.0f);
        int ya0 = (int)cy2; int ya1 = (ya0 + 1 < 32) ? ya0 + 1 : 31; float ty2 = cy2 - (float)ya0;
        float cx2 = fminf(fmaxf((ox + 0.5f) * 0.5f - 0.5f, 0.0f), 31.0f);
        int xa0 = (int)cx2; int xa1 = (xa0 + 1 < 32) ? xa0 + 1 : 31; float tx2 = cx2 - (float)xa0;
        float cy4 = fminf(fmaxf((oy + 0.5f) * 0.25f - 0.5f, 0.0f), 15.0f);
        int yb0 = (int)cy4; int yb1 = (yb0 + 1 < 16) ? yb0 + 1 : 15; float ty4 = cy4 - (float)yb0;
        float cx4 = fminf(fmaxf((ox + 0.5f) * 0.25f - 0.5f, 0.0f), 15.0f);
        int xb0 = (int)cx4; int xb1 = (xb0 + 1 < 16) ? xb0 + 1 : 15; float tx4 = cx4 - (float)xb0;
        const float* xsb = x + ((size_t)(b * C + cg2 * 16) << 12) + p;
        float* outp = out + ((size_t)(b * C + cg2 * 16) << 12) + p;
        const float* y2b = y2 + (size_t)(b * C + cg2 * 16) * 1024;
        const float* y4b = y4 + (size_t)(b * C + cg2 * 16) * 256;
        #pragma unroll 4
        for (int cc = 0; cc < 16; ++cc) {
            int c = cg2 * 16 + cc;
            const float4* wr = (const float4*)&ow_lds[c * 32];
            float a0 = 0.f, a1 = 0.f, a2 = 0.f, a3 = 0.f;
            #pragma unroll
            for (int i4 = 0; i4 < 8; ++i4) {
                float4 wv = wr[i4];
                a0 += wv.x * av[i4 * 4 + 0]; a1 += wv.y * av[i4 * 4 + 1];
                a2 += wv.z * av[i4 * 4 + 2]; a3 += wv.w * av[i4 * 4 + 3];
            }
            float o_ = ob[c] + ((a0 + a1) + (a2 + a3));
            float yv = gm * o_ + xsb[(size_t)cc << 12];
            const float* i2 = y2b + cc * 1024;
            float top2 = i2[ya0 * 32 + xa0] * (1.f - tx2) + i2[ya0 * 32 + xa1] * tx2;
            float bot2 = i2[ya1 * 32 + xa0] * (1.f - tx2) + i2[ya1 * 32 + xa1] * tx2;
            float v2 = top2 * (1.f - ty2) + bot2 * ty2;
            const float* i4p = y4b + cc * 256;
            float top4 = i4p[yb0 * 16 + xb0] * (1.f - tx4) + i4p[yb0 * 16 + xb1] * tx4;
            float bot4 = i4p[yb1 * 16 + xb0] * (1.f - tx4) + i4p[yb1 * 16 + xb1] * tx4;
            float v4 = top4 * (1.f - ty4) + bot4 * ty4;
            outp[(size_t)cc << 12] = w0 * yv + w1 * v2 + w2 * v4;
        }
    }
}

extern "C" void kernel_launch(void* const* d_in, const int* in_sizes, int n_in,
                              void* d_out, int out_size, void* d_ws, size_t ws_size,
                              hipStream_t stream) {
    const float* x     = (const float*)d_in[0];
    const float* gn_w  = (const float*)d_in[1];
    const float* gn_b  = (const float*)d_in[2];
    const float* qw    = (const float*)d_in[3];
    const float* qb    = (const float*)d_in[4];
    const float* kw    = (const float*)d_in[5];
    const float* kb    = (const float*)d_in[6];
    const float* vw    = (const float*)d_in[7];
    const float* vb    = (const float*)d_in[8];
    const float* ow    = (const float*)d_in[9];
    const float* ob    = (const float*)d_in[10];
    const float* gamma = (const float*)d_in[11];
    const float* sw    = (const float*)d_in[12];
    float* out = (float*)d_out;

    float* ws    = (float*)d_ws;
    float* xs2   = ws;                         // 524288
    float* xs4   = xs2 + 524288;               // 131072
    float* y2    = xs4 + 131072;               // 524288
    float* y4    = y2 + 524288;                // 131072
    float* part  = y4 + 131072;                // 3072
    float* pacc  = part + 3072;                // PATOT
    float* pml   = pacc + PATOT;               // PMTOT
    ushort_t* qbf = (ushort_t*)(pml + PMTOT);  // QTOT ushorts each
    ushort_t* kbf = qbf + QTOT;
    ushort_t* vbf = kbf + QTOT;

    pool_stats_kernel<<<512, 256, 0, stream>>>(x, xs2, xs4, part);
    qkv_all_kernel<<<252, 256, 0, stream>>>(x, xs2, xs4, part, gn_w, gn_b,
                                            qw, qb, kw, kb, vw, vb, qbf, kbf, vbf);
    attn_all_kernel<<<672, 256, 0, stream>>>(qbf, kbf, vbf, pacc, pml);
    comb_s24_kernel<<<160, 256, 0, stream>>>(pacc, pml, ow, ob, gamma,
                                             xs2, xs4, y2, y4);
    comb_oy_s1_fuse_kernel<<<512, 256, 0, stream>>>(pacc, pml, ow, ob, gamma,
                                                    x, y2, y4, out, sw);
}

// Round 13
// 94.337 us; speedup vs baseline: 1.1102x; 1.1102x over previous
//
#include <hip/hip_runtime.h>
#include <math.h>

#define B 4
#define C 128
#define CPG 16
#define INTER 32
#define SPLIT 16
#define KS 4

#define N1 4096
#define N2 1024
#define N4 256

// element offsets (compile-time)
#define QOFF2 (B * N1 * 32)                  // 524288
#define QOFF4 (QOFF2 + B * N2 * 32)          // 655360
#define QTOT  (QOFF4 + B * N4 * 32)          // 688128
#define PAOFF2 (B * KS * 32 * N1)            // 2097152
#define PAOFF4 (PAOFF2 + B * KS * 32 * N2)   // 2621440
#define PATOT  (PAOFF4 + B * KS * 32 * N4)   // 2752512
#define PMOFF2 (B * KS * 2 * N1)             // 131072
#define PMOFF4 (PMOFF2 + B * KS * 2 * N2)    // 163840
#define PMTOT  (PMOFF4 + B * KS * 2 * N4)    // 172032

// (1/sqrt(32)) * log2(e), folded into Q at projection time
#define QSCALE 0.25503490f

typedef unsigned short ushort_t;
typedef __attribute__((ext_vector_type(8))) short short8;
typedef __attribute__((ext_vector_type(4))) float f32x4;

__device__ __forceinline__ ushort_t f2bf(float f) {
    union { float f; unsigned u; } x; x.f = f;
    unsigned r = x.u + 0x7fffu + ((x.u >> 16) & 1u);
    return (ushort_t)(r >> 16);
}

__device__ __forceinline__ void scale_wts(const float* __restrict__ sw,
                                          float& w0, float& w1, float& w2) {
    float a = sw[0], b = sw[1], c = sw[2];
    float m = fmaxf(a, fmaxf(b, c));
    float e0 = __expf(a - m), e1 = __expf(b - m), e2 = __expf(c - m);
    float inv = 1.0f / (e0 + e1 + e2);
    w0 = e0 * inv; w1 = e1 * inv; w2 = e2 * inv;
}

__device__ __forceinline__ void block_reduce_write(float s, float q,
                                                   float* __restrict__ dst2) {
    __shared__ float rs[256], rq[256];
    rs[threadIdx.x] = s; rq[threadIdx.x] = q;
    __syncthreads();
    for (int st = 128; st > 0; st >>= 1) {
        if (threadIdx.x < st) {
            rs[threadIdx.x] += rs[threadIdx.x + st];
            rq[threadIdx.x] += rq[threadIdx.x + st];
        }
        __syncthreads();
    }
    if (threadIdx.x == 0) { dst2[0] = rs[0]; dst2[1] = rq[0]; }
}

// ---------- kernel 1: avgpool (s=2,4) fused with GN partial sums (1536 blocks) ----------
__global__ __launch_bounds__(256) void pool_stats_kernel(const float* __restrict__ x,
                                                         float* __restrict__ xs2,
                                                         float* __restrict__ xs4,
                                                         float* __restrict__ part) {
    int bid = blockIdx.x;
    if (bid < 512) {
        int sp = bid & 15, bg = bid >> 4;
        const float* base = x + ((bg * CPG) << 12) + sp * 4096;
        float s = 0.0f, q = 0.0f;
        for (int i = threadIdx.x; i < 4096; i += 256) {
            float v = base[i];
            s += v; q += v * v;
        }
        block_reduce_write(s, q, part + bid * 2);
    } else if (bid < 1024) {
        int blk = bid - 512;
        int sp = blk & 15, bg = blk >> 4;
        int bc = bg * CPG + sp;
        const float* src = x + (bc << 12);
        float* dst = xs2 + (bc << 10);
        float s = 0.0f, q = 0.0f;
        for (int p = threadIdx.x; p < 1024; p += 256) {
            int oy = p >> 5, ox = p & 31;
            const float* s2 = src + oy * 128 + ox * 2;
            float v = (s2[0] + s2[1] + s2[64] + s2[65]) * 0.25f;
            dst[p] = v; s += v; q += v * v;
        }
        block_reduce_write(s, q, part + 1024 + blk * 2);
    } else {
        int blk = bid - 1024;
        int sp = blk & 15, bg = blk >> 4;
        int bc = bg * CPG + sp;
        const float* src = x + (bc << 12);
        float* dst = xs4 + (bc << 8);
        int p = threadIdx.x & 255;
        int oy = p >> 4, ox = p & 15;
        const float* s4 = src + oy * 256 + ox * 4;
        float v = 0.0f;
        #pragma unroll
        for (int dy = 0; dy < 4; ++dy)
            #pragma unroll
            for (int dx = 0; dx < 4; ++dx) v += s4[dy * 64 + dx];
        v *= 0.0625f;
        dst[p] = v;
        block_reduce_write(v, v * v, part + 2048 + blk * 2);
    }
}

// ---------- kernel 2: QKV projection with inline GN fold -> bf16 (1008 blocks) ----------
template <int N, int NSH>
__device__ __forceinline__ void qkv_body(int bi, const float* __restrict__ xs,
    const float* __restrict__ part,
    const float* __restrict__ gn_w, const float* __restrict__ gn_b,
    const float* __restrict__ qw, const float* __restrict__ qb,
    const float* __restrict__ kw, const float* __restrict__ kb,
    const float* __restrict__ vw, const float* __restrict__ vb,
    ushort_t* __restrict__ q_bf, ushort_t* __restrict__ k_bf, ushort_t* __restrict__ v_bf) {
    const int nc = N >> 8;
    int nchunk = bi % nc; bi /= nc;
    int og = bi & 3; bi >>= 2;
    int proj = bi % 3; int b = bi / 3;
    const float* wp = (proj == 0) ? qw : ((proj == 1) ? kw : vw);
    const float* bp = (proj == 0) ? qb : ((proj == 1) ? kb : vb);
    __shared__ float wl[8 * 128];
    __shared__ float2 ss[128];
    {
        int t = threadIdx.x;
        #pragma unroll
        for (int r = 0; r < 4; ++r) {
            int e = r * 256 + t;
            int o = e >> 7, c0 = e & 127;
            wl[c0 * 8 + o] = wp[(og * 8 + o) * C + c0];
        }
        if (t < 128) {
            int c = t;
            int bg = b * 8 + (c >> 4);
            float s = 0.0f, q = 0.0f;
            #pragma unroll
            for (int sp = 0; sp < SPLIT; ++sp) {
                s += part[(bg * SPLIT + sp) * 2];
                q += part[(bg * SPLIT + sp) * 2 + 1];
            }
            float inv = 1.0f / (float)(CPG << NSH);
            float mu = s * inv;
            float var = q * inv - mu * mu;
            float a = rsqrtf(var + 1e-5f) * gn_w[c];
            float2 r; r.x = a; r.y = gn_b[c] - mu * a;
            ss[c] = r;
        }
    }
    __syncthreads();
    int n = nchunk * 256 + threadIdx.x;
    const float* xb = xs + ((size_t)(b * C) << NSH) + n;
    float acc[8];
    #pragma unroll
    for (int o = 0; o < 8; ++o) acc[o] = bp[og * 8 + o];
    #pragma unroll 2
    for (int c0 = 0; c0 < C; ++c0) {
        float raw = xb[(size_t)c0 << NSH];
        float2 s2 = ss[c0];
        float xv = fmaf(s2.x, raw, s2.y);
        const float4* wr = (const float4*)&wl[c0 * 8];
        float4 w0 = wr[0], w1 = wr[1];
        acc[0] += w0.x * xv; acc[1] += w0.y * xv; acc[2] += w0.z * xv; acc[3] += w0.w * xv;
        acc[4] += w1.x * xv; acc[5] += w1.y * xv; acc[6] += w1.z * xv; acc[7] += w1.w * xv;
    }
    if (proj < 2) {
        float fs = (proj == 0) ? QSCALE : 1.0f;
        ushort_t tmp[8];
        #pragma unroll
        for (int o = 0; o < 8; ++o) tmp[o] = f2bf(acc[o] * fs);
        ushort_t* dst = ((proj == 0) ? q_bf : k_bf) + ((size_t)(b * N + n)) * 32 + og * 8;
        *(uint4*)dst = *(const uint4*)tmp;
    } else {
        #pragma unroll
        for (int o = 0; o < 8; ++o)
            v_bf[((size_t)(b * 32 + og * 8 + o) << NSH) + n] = f2bf(acc[o]);
    }
}

__global__ __launch_bounds__(256) void qkv_all_kernel(const float* __restrict__ x,
    const float* __restrict__ xs2, const float* __restrict__ xs4,
    const float* __restrict__ part,
    const float* __restrict__ gn_w, const float* __restrict__ gn_b,
    const float* __restrict__ qw, const float* __restrict__ qb,
    const float* __restrict__ kw, const float* __restrict__ kb,
    const float* __restrict__ vw, const float* __restrict__ vb,
    ushort_t* __restrict__ qbf, ushort_t* __restrict__ kbf, ushort_t* __restrict__ vbf) {
    int bid = blockIdx.x;
    if (bid < 768) {
        qkv_body<N1, 12>(bid, x, part, gn_w, gn_b, qw, qb, kw, kb, vw, vb, qbf, kbf, vbf);
    } else if (bid < 960) {
        qkv_body<N2, 10>(bid - 768, xs2, part + 1024, gn_w + C, gn_b + C,
                         qw + INTER * C, qb + INTER, kw + INTER * C, kb + INTER,
                         vw + INTER * C, vb + INTER,
                         qbf + QOFF2, kbf + QOFF2, vbf + QOFF2);
    } else {
        qkv_body<N4, 8>(bid - 960, xs4, part + 2048, gn_w + 2 * C, gn_b + 2 * C,
                        qw + 2 * INTER * C, qb + 2 * INTER, kw + 2 * INTER * C, kb + 2 * INTER,
                        vw + 2 * INTER * C, vb + 2 * INTER,
                        qbf + QOFF4, kbf + QOFF4, vbf + QOFF4);
    }
}

// ---------- softmax + P-pack for one fragment (defer-max, exp2 domain) ----------
#define SOFTMAX_PACK(sa, mrun, lrun, aA, aB, PwF)                                              \
    {                                                                                          \
        float s_[16];                                                                          \
        _Pragma("unroll")                                                                      \
        for (int kt = 0; kt < 4; ++kt) {                                                       \
            s_[kt * 4 + 0] = sa[kt][0]; s_[kt * 4 + 1] = sa[kt][1];                            \
            s_[kt * 4 + 2] = sa[kt][2]; s_[kt * 4 + 3] = sa[kt][3];                            \
        }                                                                                      \
        float t0 = fmaxf(fmaxf(s_[0], s_[1]), s_[2]);                                          \
        float t1 = fmaxf(fmaxf(s_[3], s_[4]), s_[5]);                                          \
        float t2 = fmaxf(fmaxf(s_[6], s_[7]), s_[8]);                                          \
        float t3 = fmaxf(fmaxf(s_[9], s_[10]), s_[11]);                                        \
        float t4 = fmaxf(fmaxf(s_[12], s_[13]), s_[14]);                                       \
        float tmax = fmaxf(fmaxf(fmaxf(t0, t1), fmaxf(t2, t3)), fmaxf(t4, s_[15]));            \
        tmax = fmaxf(tmax, __shfl_xor(tmax, 16, 64));                                          \
        tmax = fmaxf(tmax, __shfl_xor(tmax, 32, 64));                                          \
        if (!__all(tmax - mrun <= 8.0f)) {                                                     \
            float nmx = fmaxf(mrun, tmax);                                                     \
            float corr = exp2f(mrun - nmx);                                                    \
            lrun *= corr;                                                                      \
            _Pragma("unroll")                                                                  \
            for (int e = 0; e < 4; ++e) { aA[e] *= corr; aB[e] *= corr; }                       \
            mrun = nmx;                                                                        \
        }                                                                                      \
        float p_[16];                                                                          \
        float psum = 0.0f;                                                                     \
        _Pragma("unroll")                                                                      \
        for (int j = 0; j < 16; ++j) { p_[j] = exp2f(s_[j] - mrun); psum += p_[j]; }           \
        psum += __shfl_xor(psum, 16, 64);                                                      \
        psum += __shfl_xor(psum, 32, 64);                                                      \
        lrun += psum;                                                                          \
        _Pragma("unroll")                                                                      \
        for (int kt = 0; kt < 4; ++kt) {                                                       \
            unsigned u01, u23;                                                                 \
            asm("v_cvt_pk_bf16_f32 %0, %1, %2" : "=v"(u01) : "v"(p_[kt * 4 + 0]), "v"(p_[kt * 4 + 1])); \
            asm("v_cvt_pk_bf16_f32 %0, %1, %2" : "=v"(u23) : "v"(p_[kt * 4 + 2]), "v"(p_[kt * 4 + 3])); \
            uint2 pv; pv.x = u01; pv.y = u23;                                                  \
            *(uint2*)&(PwF)[lq * 64 + (((kt * 32 + g * 8) ^ ((lq & 7) << 4)) >> 1)] = pv;      \
        }                                                                                      \
    }

// ---------- kernel 3: MFMA flash attention, 2 Q-fragments/wave, KS=4 (672 blocks) ----------
template <int N, int NSH>
__device__ __forceinline__ void attn_body(int bi,
    const ushort_t* __restrict__ q_bf, const ushort_t* __restrict__ k_bf,
    const ushort_t* __restrict__ v_bf,
    float* __restrict__ pacc, float* __restrict__ pml,
    ushort_t* K_lds, ushort_t* V_lds, ushort_t* P_lds) {
    int ks = bi % KS; bi /= KS;
    const int nqc = N >> 7;
    int qc = bi % nqc; int b = bi / nqc;
    int tid = threadIdx.x;
    int l = tid & 63, w = tid >> 6, lq = l & 15, g = l >> 4;
    int q0 = qc * 128 + w * 32;

    short8 qf0 = *(const short8*)(q_bf + ((size_t)(b * N + q0 + lq)) * 32 + g * 8);
    short8 qf1 = *(const short8*)(q_bf + ((size_t)(b * N + q0 + 16 + lq)) * 32 + g * 8);
    f32x4 a00 = {0.f, 0.f, 0.f, 0.f}, a01 = {0.f, 0.f, 0.f, 0.f};
    f32x4 a10 = {0.f, 0.f, 0.f, 0.f}, a11 = {0.f, 0.f, 0.f, 0.f};
    float m0 = -3.0e38f, l0 = 0.0f, m1 = -3.0e38f, l1 = 0.0f;

    const int kchunk = N / KS;
    int kbase = ks * kchunk;
    const int ntiles = kchunk >> 6;
    ushort_t* Pw = P_lds + w * (32 * 64);

    const int krow = tid >> 2;
    const int kidx = krow * 32 + ((((tid & 3) * 16) ^ ((krow & 3) << 4)) >> 1);
    const int vrow = tid >> 3;
    const int vidx = vrow * 64 + ((((tid & 7) * 16) ^ ((vrow & 7) << 4)) >> 1);

    const uint4* ksrc = (const uint4*)(k_bf + ((size_t)(b * N + kbase + krow)) * 32 + (tid & 3) * 8);
    const uint4* vsrc = (const uint4*)(v_bf + (((size_t)(b * 32 + vrow)) << NSH) + kbase + (tid & 7) * 8);
    uint4 kreg = *ksrc, vreg = *vsrc;

    const int ksw = (g ^ (lq & 3)) << 3;
    const int vsw0 = ((g * 16) ^ ((lq & 7) << 4)) >> 1;
    const int vsw1 = ((64 + g * 16) ^ ((lq & 7) << 4)) >> 1;

    for (int t = 0; t < ntiles; ++t) {
        __syncthreads();
        *(uint4*)&K_lds[kidx] = kreg;
        *(uint4*)&V_lds[vidx] = vreg;
        __syncthreads();
        if (t + 1 < ntiles) {                 // prefetch next tile under compute
            ksrc += 256; vsrc += 8;
            kreg = *ksrc; vreg = *vsrc;
        }

        f32x4 sa0[4], sa1[4];
        #pragma unroll
        for (int kt = 0; kt < 4; ++kt) {
            short8 kf = *(const short8*)&K_lds[(kt * 16 + lq) * 32 + ksw];
            f32x4 z = {0.f, 0.f, 0.f, 0.f};
            sa0[kt] = __builtin_amdgcn_mfma_f32_16x16x32_bf16(kf, qf0, z, 0, 0, 0);
            sa1[kt] = __builtin_amdgcn_mfma_f32_16x16x32_bf16(kf, qf1, z, 0, 0, 0);
        }
        SOFTMAX_PACK(sa0, m0, l0, a00, a01, Pw)
        SOFTMAX_PACK(sa1, m1, l1, a10, a11, (Pw + 16 * 64))

        short8 vf00 = *(const short8*)&V_lds[lq * 64 + vsw0];
        short8 vf10 = *(const short8*)&V_lds[(16 + lq) * 64 + vsw0];
        short8 vf01 = *(const short8*)&V_lds[lq * 64 + vsw1];
        short8 vf11 = *(const short8*)&V_lds[(16 + lq) * 64 + vsw1];
        short8 p00 = *(const short8*)&Pw[lq * 64 + vsw0];
        short8 p01 = *(const short8*)&Pw[lq * 64 + vsw1];
        short8 p10 = *(const short8*)&Pw[(16 + lq) * 64 + vsw0];
        short8 p11 = *(const short8*)&Pw[(16 + lq) * 64 + vsw1];
        a00 = __builtin_amdgcn_mfma_f32_16x16x32_bf16(vf00, p00, a00, 0, 0, 0);
        a01 = __builtin_amdgcn_mfma_f32_16x16x32_bf16(vf10, p00, a01, 0, 0, 0);
        a00 = __builtin_amdgcn_mfma_f32_16x16x32_bf16(vf01, p01, a00, 0, 0, 0);
        a01 = __builtin_amdgcn_mfma_f32_16x16x32_bf16(vf11, p01, a01, 0, 0, 0);
        a10 = __builtin_amdgcn_mfma_f32_16x16x32_bf16(vf00, p10, a10, 0, 0, 0);
        a11 = __builtin_amdgcn_mfma_f32_16x16x32_bf16(vf10, p10, a11, 0, 0, 0);
        a10 = __builtin_amdgcn_mfma_f32_16x16x32_bf16(vf01, p11, a10, 0, 0, 0);
        a11 = __builtin_amdgcn_mfma_f32_16x16x32_bf16(vf11, p11, a11, 0, 0, 0);
    }
    int n0 = q0 + lq, n1 = q0 + 16 + lq;
    size_t pb_ = ((size_t)(b * KS + ks)) * 32;
    #pragma unroll
    for (int r = 0; r < 4; ++r) {
        pacc[(pb_ + (g * 4 + r)) * N + n0]      = a00[r];
        pacc[(pb_ + 16 + (g * 4 + r)) * N + n0] = a01[r];
        pacc[(pb_ + (g * 4 + r)) * N + n1]      = a10[r];
        pacc[(pb_ + 16 + (g * 4 + r)) * N + n1] = a11[r];
    }
    if (g == 0) {
        pml[((size_t)(b * KS + ks) * 2) * N + n0]     = m0;
        pml[((size_t)(b * KS + ks) * 2 + 1) * N + n0] = l0;
        pml[((size_t)(b * KS + ks) * 2) * N + n1]     = m1;
        pml[((size_t)(b * KS + ks) * 2 + 1) * N + n1] = l1;
    }
}

__global__ __launch_bounds__(256) void attn_all_kernel(
    const ushort_t* __restrict__ qbf, const ushort_t* __restrict__ kbf,
    const ushort_t* __restrict__ vbf,
    float* __restrict__ pacc, float* __restrict__ pml) {
    __shared__ ushort_t K_lds[64 * 32];        // 4 KB
    __shared__ ushort_t V_lds[32 * 64];        // 4 KB
    __shared__ ushort_t P_lds[4 * 32 * 64];    // 16 KB
    int bid = blockIdx.x;
    if (bid < 512) {
        attn_body<N1, 12>(bid, qbf, kbf, vbf, pacc, pml, K_lds, V_lds, P_lds);
    } else if (bid < 640) {
        attn_body<N2, 10>(bid - 512, qbf + QOFF2, kbf + QOFF2, vbf + QOFF2,
                          pacc + PAOFF2, pml + PMOFF2, K_lds, V_lds, P_lds);
    } else {
        attn_body<N4, 8>(bid - 640, qbf + QOFF4, kbf + QOFF4, vbf + QOFF4,
                         pacc + PAOFF4, pml + PMOFF4, K_lds, V_lds, P_lds);
    }
}

// ---------- kernel 4: combine + oy + residual for s=2/s=4 (160 blocks) ----------
template <int N, int NSH>
__device__ __forceinline__ void comb_oy_body(int tile, const float* __restrict__ pacc,
    const float* __restrict__ pml, const float* __restrict__ ow, const float* __restrict__ ob,
    const float* __restrict__ gamma, const float* __restrict__ xs,
    float* __restrict__ ydst, float* att_lds, float* ow_lds) {
    const int ntiles = N >> 5;
    int b = tile / ntiles;
    int n0 = (tile % ntiles) << 5;
    int t = threadIdx.x;
    {
        const float4* src = (const float4*)ow;
        float4* dst = (float4*)ow_lds;
        dst[t] = src[t]; dst[256 + t] = src[256 + t];
        dst[512 + t] = src[512 + t]; dst[768 + t] = src[768 + t];
    }
    {
        int o = t >> 3, j = t & 7;
        int n = n0 + j * 4;
        float4 mv[KS];
        float4 M = {-3.0e38f, -3.0e38f, -3.0e38f, -3.0e38f};
        #pragma unroll
        for (int k2 = 0; k2 < KS; ++k2) {
            mv[k2] = *(const float4*)&pml[((size_t)(b * KS + k2) * 2) * N + n];
            M.x = fmaxf(M.x, mv[k2].x); M.y = fmaxf(M.y, mv[k2].y);
            M.z = fmaxf(M.z, mv[k2].z); M.w = fmaxf(M.w, mv[k2].w);
        }
        float4 L = {0.f, 0.f, 0.f, 0.f}, A = {0.f, 0.f, 0.f, 0.f};
        #pragma unroll
        for (int k2 = 0; k2 < KS; ++k2) {
            float4 lv = *(const float4*)&pml[((size_t)(b * KS + k2) * 2 + 1) * N + n];
            float4 av = *(const float4*)&pacc[((size_t)(b * KS + k2) * INTER + o) * N + n];
            float4 wg;                         // log2-domain m -> exp2
            wg.x = exp2f(mv[k2].x - M.x); wg.y = exp2f(mv[k2].y - M.y);
            wg.z = exp2f(mv[k2].z - M.z); wg.w = exp2f(mv[k2].w - M.w);
            L.x += lv.x * wg.x; L.y += lv.y * wg.y;
            L.z += lv.z * wg.z; L.w += lv.w * wg.w;
            A.x += av.x * wg.x; A.y += av.y * wg.y;
            A.z += av.z * wg.z; A.w += av.w * wg.w;
        }
        float4 r;
        r.x = A.x / L.x; r.y = A.y / L.y; r.z = A.z / L.z; r.w = A.w / L.w;
        *(float4*)&att_lds[o * 36 + j * 4] = r;
    }
    __syncthreads();
    {
        int n = t & 31, cg2 = t >> 5;
        float av[32];
        #pragma unroll
        for (int i = 0; i < 32; ++i) av[i] = att_lds[i * 36 + n];
        float gm = gamma[0];
        const float* xsb = xs + ((size_t)(b * C + cg2 * 16) << NSH) + n0 + n;
        float* yb = ydst + ((size_t)(b * C + cg2 * 16) << NSH) + n0 + n;
        #pragma unroll 4
        for (int cc = 0; cc < 16; ++cc) {
            int c = cg2 * 16 + cc;
            const float4* wr = (const float4*)&ow_lds[c * 32];
            float a0 = 0.f, a1 = 0.f, a2 = 0.f, a3 = 0.f;
            #pragma unroll
            for (int i4 = 0; i4 < 8; ++i4) {
                float4 wv = wr[i4];
                a0 += wv.x * av[i4 * 4 + 0]; a1 += wv.y * av[i4 * 4 + 1];
                a2 += wv.z * av[i4 * 4 + 2]; a3 += wv.w * av[i4 * 4 + 3];
            }
            float o_ = ob[c] + ((a0 + a1) + (a2 + a3));
            yb[(size_t)cc << NSH] = gm * o_ + xsb[(size_t)cc << NSH];
        }
    }
}

__global__ __launch_bounds__(256) void comb_s24_kernel(const float* __restrict__ pacc,
    const float* __restrict__ pml,
    const float* __restrict__ ow, const float* __restrict__ ob,
    const float* __restrict__ gamma,
    const float* __restrict__ xs2, const float* __restrict__ xs4,
    float* __restrict__ y2, float* __restrict__ y4) {
    __shared__ float att_lds[32 * 36];
    __shared__ float ow_lds[128 * 32];
    int bid = blockIdx.x;
    if (bid < 128) {
        comb_oy_body<N2, 10>(bid, pacc + PAOFF2, pml + PMOFF2,
                             ow + C * INTER, ob + C, gamma + 1, xs2, y2, att_lds, ow_lds);
    } else {
        comb_oy_body<N4, 8>(bid - 128, pacc + PAOFF4, pml + PMOFF4,
                            ow + 2 * C * INTER, ob + 2 * C, gamma + 2, xs4, y4,
                            att_lds, ow_lds);
    }
}

// ---------- kernel 5: s=1 combine + oy + residual + bilinear fuse (512 blocks) ----------
__global__ __launch_bounds__(256) void comb_oy_s1_fuse_kernel(
    const float* __restrict__ pacc, const float* __restrict__ pml,
    const float* __restrict__ ow, const float* __restrict__ ob,
    const float* __restrict__ gamma, const float* __restrict__ x,
    const float* __restrict__ y2, const float* __restrict__ y4,
    float* __restrict__ out, const float* __restrict__ sw) {
    __shared__ float att_lds[32 * 36];
    __shared__ float ow_lds[128 * 32];
    const int N = N1;
    int tile = blockIdx.x;
    int b = tile >> 7;
    int n0 = (tile & 127) << 5;
    int t = threadIdx.x;
    {
        const float4* src = (const float4*)ow;
        float4* dst = (float4*)ow_lds;
        dst[t] = src[t]; dst[256 + t] = src[256 + t];
        dst[512 + t] = src[512 + t]; dst[768 + t] = src[768 + t];
    }
    {
        int o = t >> 3, j = t & 7;
        int n = n0 + j * 4;
        float4 mv[KS];
        float4 M = {-3.0e38f, -3.0e38f, -3.0e38f, -3.0e38f};
        #pragma unroll
        for (int k2 = 0; k2 < KS; ++k2) {
            mv[k2] = *(const float4*)&pml[((size_t)(b * KS + k2) * 2) * N + n];
            M.x = fmaxf(M.x, mv[k2].x); M.y = fmaxf(M.y, mv[k2].y);
            M.z = fmaxf(M.z, mv[k2].z); M.w = fmaxf(M.w, mv[k2].w);
        }
        float4 L = {0.f, 0.f, 0.f, 0.f}, A = {0.f, 0.f, 0.f, 0.f};
        #pragma unroll
        for (int k2 = 0; k2 < KS; ++k2) {
            float4 lv = *(const float4*)&pml[((size_t)(b * KS + k2) * 2 + 1) * N + n];
            float4 av = *(const float4*)&pacc[((size_t)(b * KS + k2) * INTER + o) * N + n];
            float4 wg;                          // log2-domain m -> exp2
            wg.x = exp2f(mv[k2].x - M.x); wg.y = exp2f(mv[k2].y - M.y);
            wg.z = exp2f(mv[k2].z - M.z); wg.w = exp2f(mv[k2].w - M.w);
            L.x += lv.x * wg.x; L.y += lv.y * wg.y;
            L.z += lv.z * wg.z; L.w += lv.w * wg.w;
            A.x += av.x * wg.x; A.y += av.y * wg.y;
            A.z += av.z * wg.z; A.w += av.w * wg.w;
        }
        float4 r;
        r.x = A.x / L.x; r.y = A.y / L.y; r.z = A.z / L.z; r.w = A.w / L.w;
        *(float4*)&att_lds[o * 36 + j * 4] = r;
    }
    __syncthreads();
    {
        int n = t & 31, cg2 = t >> 5;
        float av[32];
        #pragma unroll
        for (int i = 0; i < 32; ++i) av[i] = att_lds[i * 36 + n];
        float gm = gamma[0];
        float w0, w1, w2; scale_wts(sw, w0, w1, w2);
        int p = n0 + n, oy = p >> 6, ox = p & 63;
        float cy2 = fminf(fmaxf((oy + 0.5f) * 0.5f - 0.5f, 0.0f), 31.0f);
        int ya0 = (int)cy2; int ya1 = (ya0 + 1 < 32) ? ya0 + 1 : 31; float ty2 = cy2 - (float)ya0;
        float cx2 = fminf(fmaxf((ox + 0.5f) * 0.5f - 0.5f, 0.0f), 31.0f);
        int xa0 = (int)cx2; int xa1 = (xa0 + 1 < 32) ? xa0 + 1 : 31; float tx2 = cx2 - (float)xa0;
        float cy4 = fminf(fmaxf((oy + 0.5f) * 0.25f - 0.5f, 0.0f), 15.0f);
        int yb0 = (int)cy4; int yb1 = (yb0 + 1 < 16) ? yb0 + 1 : 15; float ty4 = cy4 - (float)yb0;
        float cx4 = fminf(fmaxf((ox + 0.5f) * 0.25f - 0.5f, 0.0f), 15.0f);
        int xb0 = (int)cx4; int xb1 = (xb0 + 1 < 16) ? xb0 + 1 : 15; float tx4 = cx4 - (float)xb0;
        const float* xsb = x + ((size_t)(b * C + cg2 * 16) << 12) + p;
        float* outp = out + ((size_t)(b * C + cg2 * 16) << 12) + p;
        const float* y2b = y2 + (size_t)(b * C + cg2 * 16) * 1024;
        const float* y4b = y4 + (size_t)(b * C + cg2 * 16) * 256;
        #pragma unroll 4
        for (int cc = 0; cc < 16; ++cc) {
            int c = cg2 * 16 + cc;
            const float4* wr = (const float4*)&ow_lds[c * 32];
            float a0 = 0.f, a1 = 0.f, a2 = 0.f, a3 = 0.f;
            #pragma unroll
            for (int i4 = 0; i4 < 8; ++i4) {
                float4 wv = wr[i4];
                a0 += wv.x * av[i4 * 4 + 0]; a1 += wv.y * av[i4 * 4 + 1];
                a2 += wv.z * av[i4 * 4 + 2]; a3 += wv.w * av[i4 * 4 + 3];
            }
            float o_ = ob[c] + ((a0 + a1) + (a2 + a3));
            float yv = gm * o_ + xsb[(size_t)cc << 12];
            const float* i2 = y2b + cc * 1024;
            float top2 = i2[ya0 * 32 + xa0] * (1.f - tx2) + i2[ya0 * 32 + xa1] * tx2;
            float bot2 = i2[ya1 * 32 + xa0] * (1.f - tx2) + i2[ya1 * 32 + xa1] * tx2;
            float v2 = top2 * (1.f - ty2) + bot2 * ty2;
            const float* i4p = y4b + cc * 256;
            float top4 = i4p[yb0 * 16 + xb0] * (1.f - tx4) + i4p[yb0 * 16 + xb1] * tx4;
            float bot4 = i4p[yb1 * 16 + xb0] * (1.f - tx4) + i4p[yb1 * 16 + xb1] * tx4;
            float v4 = top4 * (1.f - ty4) + bot4 * ty4;
            outp[(size_t)cc << 12] = w0 * yv + w1 * v2 + w2 * v4;
        }
    }
}

extern "C" void kernel_launch(void* const* d_in, const int* in_sizes, int n_in,
                              void* d_out, int out_size, void* d_ws, size_t ws_size,
                              hipStream_t stream) {
    const float* x     = (const float*)d_in[0];
    const float* gn_w  = (const float*)d_in[1];
    const float* gn_b  = (const float*)d_in[2];
    const float* qw    = (const float*)d_in[3];
    const float* qb    = (const float*)d_in[4];
    const float* kw    = (const float*)d_in[5];
    const float* kb    = (const float*)d_in[6];
    const float* vw    = (const float*)d_in[7];
    const float* vb    = (const float*)d_in[8];
    const float* ow    = (const float*)d_in[9];
    const float* ob    = (const float*)d_in[10];
    const float* gamma = (const float*)d_in[11];
    const float* sw    = (const float*)d_in[12];
    float* out = (float*)d_out;

    float* ws    = (float*)d_ws;
    float* xs2   = ws;                         // 524288
    float* xs4   = xs2 + 524288;               // 131072
    float* y2    = xs4 + 131072;               // 524288
    float* y4    = y2 + 524288;                // 131072
    float* part  = y4 + 131072;                // 3072
    float* pacc  = part + 3072;                // PATOT
    float* pml   = pacc + PATOT;               // PMTOT
    ushort_t* qbf = (ushort_t*)(pml + PMTOT);  // QTOT ushorts each
    ushort_t* kbf = qbf + QTOT;
    ushort_t* vbf = kbf + QTOT;

    pool_stats_kernel<<<1536, 256, 0, stream>>>(x, xs2, xs4, part);
    qkv_all_kernel<<<1008, 256, 0, stream>>>(x, xs2, xs4, part, gn_w, gn_b,
                                             qw, qb, kw, kb, vw, vb, qbf, kbf, vbf);
    attn_all_kernel<<<672, 256, 0, stream>>>(qbf, kbf, vbf, pacc, pml);
    comb_s24_kernel<<<160, 256, 0, stream>>>(pacc, pml, ow, ob, gamma,
                                             xs2, xs4, y2, y4);
    comb_oy_s1_fuse_kernel<<<512, 256, 0, stream>>>(pacc, pml, ow, ob, gamma,
                                                    x, y2, y4, out, sw);
}

// Round 14
// 81.848 us; speedup vs baseline: 1.2796x; 1.1526x over previous
//
#include <hip/hip_runtime.h>
#include <math.h>

#define B 4
#define C 128
#define CPG 16
#define INTER 32
#define SPLIT 16
#define KS 4

#define N1 4096
#define N2 1024
#define N4 256

// element offsets (compile-time)
#define QOFF2 (B * N1 * 32)                  // 524288
#define QOFF4 (QOFF2 + B * N2 * 32)          // 655360
#define QTOT  (QOFF4 + B * N4 * 32)          // 688128
#define PAOFF2 (B * KS * 32 * N1)            // 2097152
#define PAOFF4 (PAOFF2 + B * KS * 32 * N2)   // 2621440
#define PATOT  (PAOFF4 + B * KS * 32 * N4)   // 2752512
#define PMOFF2 (B * KS * 2 * N1)             // 131072
#define PMOFF4 (PMOFF2 + B * KS * 2 * N2)    // 163840
#define PMTOT  (PMOFF4 + B * KS * 2 * N4)    // 172032

typedef unsigned short ushort_t;
typedef __attribute__((ext_vector_type(8))) short short8;
typedef __attribute__((ext_vector_type(4))) short short4v;
typedef __attribute__((ext_vector_type(4))) float f32x4;

__device__ __forceinline__ ushort_t f2bf(float f) {
    union { float f; unsigned u; } x; x.f = f;
    unsigned r = x.u + 0x7fffu + ((x.u >> 16) & 1u);
    return (ushort_t)(r >> 16);
}

__device__ __forceinline__ void scale_wts(const float* __restrict__ sw,
                                          float& w0, float& w1, float& w2) {
    float a = sw[0], b = sw[1], c = sw[2];
    float m = fmaxf(a, fmaxf(b, c));
    float e0 = __expf(a - m), e1 = __expf(b - m), e2 = __expf(c - m);
    float inv = 1.0f / (e0 + e1 + e2);
    w0 = e0 * inv; w1 = e1 * inv; w2 = e2 * inv;
}

__device__ __forceinline__ void block_reduce_write(float s, float q,
                                                   float* __restrict__ dst2) {
    __shared__ float rs[256], rq[256];
    rs[threadIdx.x] = s; rq[threadIdx.x] = q;
    __syncthreads();
    for (int st = 128; st > 0; st >>= 1) {
        if (threadIdx.x < st) {
            rs[threadIdx.x] += rs[threadIdx.x + st];
            rq[threadIdx.x] += rq[threadIdx.x + st];
        }
        __syncthreads();
    }
    if (threadIdx.x == 0) { dst2[0] = rs[0]; dst2[1] = rq[0]; }
}

// ---------- kernel 1: avgpool (s=2,4) fused with GN partial sums ----------
__global__ __launch_bounds__(256) void pool_stats_kernel(const float* __restrict__ x,
                                                         float* __restrict__ xs2,
                                                         float* __restrict__ xs4,
                                                         float* __restrict__ part) {
    int bid = blockIdx.x;
    if (bid < 512) {
        // s=1 stats on x
        int sp = bid & 15, bg = bid >> 4;
        const float* base = x + ((bg * CPG) << 12) + sp * 4096;
        float s = 0.0f, q = 0.0f;
        for (int i = threadIdx.x; i < 4096; i += 256) {
            float v = base[i];
            s += v; q += v * v;
        }
        block_reduce_write(s, q, part + bid * 2);
    } else if (bid < 1024) {
        // s=2: one channel plane per block: pool 64x64 -> 32x32 + stats
        int blk = bid - 512;
        int sp = blk & 15, bg = blk >> 4;
        int bc = bg * CPG + sp;            // == b*C + c
        const float* src = x + (bc << 12);
        float* dst = xs2 + (bc << 10);
        float s = 0.0f, q = 0.0f;
        for (int p = threadIdx.x; p < 1024; p += 256) {
            int oy = p >> 5, ox = p & 31;
            const float* s2 = src + oy * 128 + ox * 2;
            float v = (s2[0] + s2[1] + s2[64] + s2[65]) * 0.25f;
            dst[p] = v; s += v; q += v * v;
        }
        block_reduce_write(s, q, part + 1024 + blk * 2);
    } else {
        // s=4: one channel plane per block: pool 64x64 -> 16x16 + stats
        int blk = bid - 1024;
        int sp = blk & 15, bg = blk >> 4;
        int bc = bg * CPG + sp;
        const float* src = x + (bc << 12);
        float* dst = xs4 + (bc << 8);
        float s = 0.0f, q = 0.0f;
        if (threadIdx.x < 256) {
            int p = threadIdx.x;
            int oy = p >> 4, ox = p & 15;
            const float* s4 = src + oy * 256 + ox * 4;
            float v = 0.0f;
            #pragma unroll
            for (int dy = 0; dy < 4; ++dy)
                #pragma unroll
                for (int dx = 0; dx < 4; ++dx) v += s4[dy * 64 + dx];
            v *= 0.0625f;
            dst[p] = v; s = v; q = v * v;
        }
        block_reduce_write(s, q, part + 2048 + blk * 2);
    }
}

// ---------- kernel 2: QKV projection with inline GN fold -> bf16 ----------
template <int N, int NSH>
__device__ __forceinline__ void qkv_body(int bi, const float* __restrict__ xs,
    const float* __restrict__ part,
    const float* __restrict__ gn_w, const float* __restrict__ gn_b,
    const float* __restrict__ qw, const float* __restrict__ qb,
    const float* __restrict__ kw, const float* __restrict__ kb,
    const float* __restrict__ vw, const float* __restrict__ vb,
    ushort_t* __restrict__ q_bf, ushort_t* __restrict__ k_bf, ushort_t* __restrict__ v_bf) {
    const int nc = N >> 8;
    int nchunk = bi % nc; bi /= nc;
    int og = bi & 3; bi >>= 2;
    int proj = bi % 3; int b = bi / 3;
    const float* wp = (proj == 0) ? qw : ((proj == 1) ? kw : vw);
    const float* bp = (proj == 0) ? qb : ((proj == 1) ? kb : vb);
    __shared__ float wl[8 * 128];
    __shared__ float2 ss[128];
    {
        int t = threadIdx.x;
        #pragma unroll
        for (int r = 0; r < 4; ++r) {
            int e = r * 256 + t;
            int o = e >> 7, c0 = e & 127;
            wl[c0 * 8 + o] = wp[(og * 8 + o) * C + c0];
        }
        if (t < 128) {
            int c = t;
            int bg = b * 8 + (c >> 4);
            float s = 0.0f, q = 0.0f;
            #pragma unroll
            for (int sp = 0; sp < SPLIT; ++sp) {
                s += part[(bg * SPLIT + sp) * 2];
                q += part[(bg * SPLIT + sp) * 2 + 1];
            }
            float inv = 1.0f / (float)(CPG << NSH);
            float mu = s * inv;
            float var = q * inv - mu * mu;
            float a = rsqrtf(var + 1e-5f) * gn_w[c];
            float2 r; r.x = a; r.y = gn_b[c] - mu * a;
            ss[c] = r;
        }
    }
    __syncthreads();
    int n = nchunk * 256 + threadIdx.x;
    const float* xb = xs + ((size_t)(b * C) << NSH) + n;
    float acc[8];
    #pragma unroll
    for (int o = 0; o < 8; ++o) acc[o] = bp[og * 8 + o];
    #pragma unroll 2
    for (int c0 = 0; c0 < C; ++c0) {
        float raw = xb[(size_t)c0 << NSH];
        float2 s2 = ss[c0];
        float xv = fmaf(s2.x, raw, s2.y);
        const float4* wr = (const float4*)&wl[c0 * 8];
        float4 w0 = wr[0], w1 = wr[1];
        acc[0] += w0.x * xv; acc[1] += w0.y * xv; acc[2] += w0.z * xv; acc[3] += w0.w * xv;
        acc[4] += w1.x * xv; acc[5] += w1.y * xv; acc[6] += w1.z * xv; acc[7] += w1.w * xv;
    }
    if (proj < 2) {
        ushort_t tmp[8];
        #pragma unroll
        for (int o = 0; o < 8; ++o) tmp[o] = f2bf(acc[o]);
        ushort_t* dst = ((proj == 0) ? q_bf : k_bf) + ((size_t)(b * N + n)) * 32 + og * 8;
        *(uint4*)dst = *(const uint4*)tmp;
    } else {
        #pragma unroll
        for (int o = 0; o < 8; ++o)
            v_bf[((size_t)(b * 32 + og * 8 + o) << NSH) + n] = f2bf(acc[o]);
    }
}

__global__ __launch_bounds__(256) void qkv_all_kernel(const float* __restrict__ x,
    const float* __restrict__ xs2, const float* __restrict__ xs4,
    const float* __restrict__ part,
    const float* __restrict__ gn_w, const float* __restrict__ gn_b,
    const float* __restrict__ qw, const float* __restrict__ qb,
    const float* __restrict__ kw, const float* __restrict__ kb,
    const float* __restrict__ vw, const float* __restrict__ vb,
    ushort_t* __restrict__ qbf, ushort_t* __restrict__ kbf, ushort_t* __restrict__ vbf) {
    int bid = blockIdx.x;
    if (bid < 768) {
        qkv_body<N1, 12>(bid, x, part, gn_w, gn_b, qw, qb, kw, kb, vw, vb, qbf, kbf, vbf);
    } else if (bid < 960) {
        qkv_body<N2, 10>(bid - 768, xs2, part + 1024, gn_w + C, gn_b + C,
                         qw + INTER * C, qb + INTER, kw + INTER * C, kb + INTER,
                         vw + INTER * C, vb + INTER,
                         qbf + QOFF2, kbf + QOFF2, vbf + QOFF2);
    } else {
        qkv_body<N4, 8>(bid - 960, xs4, part + 2048, gn_w + 2 * C, gn_b + 2 * C,
                        qw + 2 * INTER * C, qb + 2 * INTER, kw + 2 * INTER * C, kb + 2 * INTER,
                        vw + 2 * INTER * C, vb + 2 * INTER,
                        qbf + QOFF4, kbf + QOFF4, vbf + QOFF4);
    }
}

// ---------- kernel 3: MFMA flash attention (split-K), all scales ----------
template <int N, int NSH>
__device__ __forceinline__ void attn_body(int bi,
    const ushort_t* __restrict__ q_bf, const ushort_t* __restrict__ k_bf,
    const ushort_t* __restrict__ v_bf,
    float* __restrict__ pacc, float* __restrict__ pml,
    ushort_t* K_lds, ushort_t* V_lds, ushort_t* P_lds) {
    int ks = bi % KS; bi /= KS;
    const int nqc = N >> 6;
    int qc = bi % nqc; int b = bi / nqc;
    int tid = threadIdx.x;
    int l = tid & 63, w = tid >> 6, lq = l & 15, g = l >> 4;
    int q0 = qc * 64 + w * 16;
    const float invs = 0.17677669529663687f;   // 1/sqrt(32)

    short8 qf = *(const short8*)(q_bf + ((size_t)(b * N + q0 + lq)) * 32 + g * 8);
    f32x4 acco0 = {0.f, 0.f, 0.f, 0.f}, acco1 = {0.f, 0.f, 0.f, 0.f};
    float mrun = -3.0e38f, lrun = 0.0f;

    const int kchunk = N / KS;
    int kbase = ks * kchunk;
    const int ntiles = kchunk >> 6;
    ushort_t* Pw = P_lds + w * 16 * 72;

    for (int t = 0; t < ntiles; ++t) {
        int kt0 = kbase + t * 64;
        __syncthreads();
        {
            const uint4* ksrc = (const uint4*)(k_bf + ((size_t)(b * N + kt0 + (tid >> 2))) * 32 + (tid & 3) * 8);
            *(uint4*)&K_lds[(tid >> 2) * 40 + (tid & 3) * 8] = *ksrc;
            const uint4* vsrc = (const uint4*)(v_bf + (((size_t)(b * 32 + (tid >> 3))) << NSH) + kt0 + (tid & 7) * 8);
            *(uint4*)&V_lds[(tid >> 3) * 72 + (tid & 7) * 8] = *vsrc;
        }
        __syncthreads();

        f32x4 sa[4];
        #pragma unroll
        for (int kt = 0; kt < 4; ++kt) {
            short8 kf = *(const short8*)&K_lds[(kt * 16 + lq) * 40 + g * 8];
            f32x4 z = {0.f, 0.f, 0.f, 0.f};
            sa[kt] = __builtin_amdgcn_mfma_f32_16x16x32_bf16(kf, qf, z, 0, 0, 0);
        }
        float sc[16];
        #pragma unroll
        for (int kt = 0; kt < 4; ++kt) {
            sc[kt * 4 + 0] = sa[kt][0] * invs;
            sc[kt * 4 + 1] = sa[kt][1] * invs;
            sc[kt * 4 + 2] = sa[kt][2] * invs;
            sc[kt * 4 + 3] = sa[kt][3] * invs;
        }
        float tmax = sc[0];
        #pragma unroll
        for (int j = 1; j < 16; ++j) tmax = fmaxf(tmax, sc[j]);
        tmax = fmaxf(tmax, __shfl_xor(tmax, 16, 64));
        tmax = fmaxf(tmax, __shfl_xor(tmax, 32, 64));
        float nm = fmaxf(mrun, tmax);
        float corr = __expf(mrun - nm);
        float psum = 0.0f;
        ushort_t pb[16];
        #pragma unroll
        for (int j = 0; j < 16; ++j) {
            float p = __expf(sc[j] - nm);
            psum += p;
            pb[j] = f2bf(p);
        }
        psum += __shfl_xor(psum, 16, 64);
        psum += __shfl_xor(psum, 32, 64);
        lrun = lrun * corr + psum;
        mrun = nm;
        #pragma unroll
        for (int e = 0; e < 4; ++e) { acco0[e] *= corr; acco1[e] *= corr; }
        #pragma unroll
        for (int kt = 0; kt < 4; ++kt) {
            short4v pv4;
            pv4[0] = (short)pb[kt * 4 + 0];
            pv4[1] = (short)pb[kt * 4 + 1];
            pv4[2] = (short)pb[kt * 4 + 2];
            pv4[3] = (short)pb[kt * 4 + 3];
            *(short4v*)&Pw[lq * 72 + kt * 16 + g * 4] = pv4;
        }
        #pragma unroll
        for (int c = 0; c < 2; ++c) {
            short8 pf  = *(const short8*)&Pw[lq * 72 + c * 32 + g * 8];
            short8 vf0 = *(const short8*)&V_lds[(lq) * 72 + c * 32 + g * 8];
            short8 vf1 = *(const short8*)&V_lds[(16 + lq) * 72 + c * 32 + g * 8];
            acco0 = __builtin_amdgcn_mfma_f32_16x16x32_bf16(vf0, pf, acco0, 0, 0, 0);
            acco1 = __builtin_amdgcn_mfma_f32_16x16x32_bf16(vf1, pf, acco1, 0, 0, 0);
        }
    }
    int n = q0 + lq;
    size_t pb_ = ((size_t)(b * KS + ks)) * 32;
    #pragma unroll
    for (int r = 0; r < 4; ++r) {
        pacc[(pb_ + (g * 4 + r)) * N + n]      = acco0[r];
        pacc[(pb_ + 16 + (g * 4 + r)) * N + n] = acco1[r];
    }
    if (g == 0) {
        pml[((size_t)(b * KS + ks) * 2) * N + n]     = mrun;
        pml[((size_t)(b * KS + ks) * 2 + 1) * N + n] = lrun;
    }
}

__global__ __launch_bounds__(256) void attn_all_kernel(
    const ushort_t* __restrict__ qbf, const ushort_t* __restrict__ kbf,
    const ushort_t* __restrict__ vbf,
    float* __restrict__ pacc, float* __restrict__ pml) {
    __shared__ ushort_t K_lds[64 * 40];
    __shared__ ushort_t V_lds[32 * 72];
    __shared__ ushort_t P_lds[4 * 16 * 72];
    int bid = blockIdx.x;
    if (bid < 1024) {
        attn_body<N1, 12>(bid, qbf, kbf, vbf, pacc, pml, K_lds, V_lds, P_lds);
    } else if (bid < 1280) {
        attn_body<N2, 10>(bid - 1024, qbf + QOFF2, kbf + QOFF2, vbf + QOFF2,
                          pacc + PAOFF2, pml + PMOFF2, K_lds, V_lds, P_lds);
    } else {
        attn_body<N4, 8>(bid - 1280, qbf + QOFF4, kbf + QOFF4, vbf + QOFF4,
                         pacc + PAOFF4, pml + PMOFF4, K_lds, V_lds, P_lds);
    }
}

// ---------- kernel 4: split-K combine + output projection + residual, fused ----------
template <int N, int NSH>
__device__ __forceinline__ void comb_oy_body(int tile, const float* __restrict__ pacc,
                                             const float* __restrict__ pml,
                                             const float* __restrict__ ow,
                                             const float* __restrict__ ob,
                                             const float* __restrict__ gamma,
                                             const float* __restrict__ xs,
                                             float* __restrict__ ydst,
                                             const float* __restrict__ sw,
                                             float* att_lds, float* ow_lds) {
    const int ntiles = N >> 5;
    int b = tile / ntiles;
    int n0 = (tile % ntiles) << 5;
    int t = threadIdx.x;
    {
        const float4* src = (const float4*)ow;
        float4* dst = (float4*)ow_lds;
        dst[t] = src[t];
        dst[256 + t] = src[256 + t];
        dst[512 + t] = src[512 + t];
        dst[768 + t] = src[768 + t];
    }
    {
        int o = t >> 3, j = t & 7;
        int n = n0 + j * 4;
        float4 mv[KS], lv[KS], av[KS];
        float4 M = {-3.0e38f, -3.0e38f, -3.0e38f, -3.0e38f};
        #pragma unroll
        for (int ks = 0; ks < KS; ++ks) {
            mv[ks] = *(const float4*)&pml[((size_t)(b * KS + ks) * 2) * N + n];
            lv[ks] = *(const float4*)&pml[((size_t)(b * KS + ks) * 2 + 1) * N + n];
            av[ks] = *(const float4*)&pacc[((size_t)(b * KS + ks) * INTER + o) * N + n];
            M.x = fmaxf(M.x, mv[ks].x); M.y = fmaxf(M.y, mv[ks].y);
            M.z = fmaxf(M.z, mv[ks].z); M.w = fmaxf(M.w, mv[ks].w);
        }
        float4 L = {0.f, 0.f, 0.f, 0.f}, A = {0.f, 0.f, 0.f, 0.f};
        #pragma unroll
        for (int ks = 0; ks < KS; ++ks) {
            float4 wgt;
            wgt.x = __expf(mv[ks].x - M.x); wgt.y = __expf(mv[ks].y - M.y);
            wgt.z = __expf(mv[ks].z - M.z); wgt.w = __expf(mv[ks].w - M.w);
            L.x += lv[ks].x * wgt.x; L.y += lv[ks].y * wgt.y;
            L.z += lv[ks].z * wgt.z; L.w += lv[ks].w * wgt.w;
            A.x += av[ks].x * wgt.x; A.y += av[ks].y * wgt.y;
            A.z += av[ks].z * wgt.z; A.w += av[ks].w * wgt.w;
        }
        float4 r;
        r.x = A.x / L.x; r.y = A.y / L.y; r.z = A.z / L.z; r.w = A.w / L.w;
        *(float4*)&att_lds[o * 36 + j * 4] = r;
    }
    __syncthreads();
    {
        int n = t & 31;
        int cg = t >> 5;
        float av[INTER];
        #pragma unroll
        for (int i = 0; i < INTER; ++i) av[i] = att_lds[i * 36 + n];
        float gm = gamma[0];
        float wsc = 1.0f;
        bool scale = (sw != nullptr);
        if (scale) { float w0, w1, w2; scale_wts(sw, w0, w1, w2); wsc = w0; }
        const float* xsb = xs + ((size_t)(b * C + cg * 16) << NSH) + n0 + n;
        float* yb = ydst + ((size_t)(b * C + cg * 16) << NSH) + n0 + n;
        #pragma unroll
        for (int cc = 0; cc < 16; ++cc) {
            int c = cg * 16 + cc;
            const float4* wr = (const float4*)&ow_lds[c * 32];
            float a0 = 0.f, a1 = 0.f, a2 = 0.f, a3 = 0.f;
            #pragma unroll
            for (int i4 = 0; i4 < 8; ++i4) {
                float4 wv = wr[i4];
                a0 += wv.x * av[i4 * 4 + 0];
                a1 += wv.y * av[i4 * 4 + 1];
                a2 += wv.z * av[i4 * 4 + 2];
                a3 += wv.w * av[i4 * 4 + 3];
            }
            float o = ob[c] + ((a0 + a1) + (a2 + a3));
            float y = gm * o + xsb[(size_t)cc << NSH];
            yb[(size_t)cc << NSH] = wsc * y;
        }
    }
}

__global__ __launch_bounds__(256) void comb_oy_all_kernel(const float* __restrict__ pacc,
    const float* __restrict__ pml,
    const float* __restrict__ ow, const float* __restrict__ ob,
    const float* __restrict__ gamma,
    const float* __restrict__ x, const float* __restrict__ xs2, const float* __restrict__ xs4,
    float* __restrict__ out, float* __restrict__ y2, float* __restrict__ y4,
    const float* __restrict__ sw) {
    __shared__ float att_lds[32 * 36];
    __shared__ float ow_lds[128 * 32];
    int bid = blockIdx.x;
    if (bid < 512) {
        comb_oy_body<N1, 12>(bid, pacc, pml, ow, ob, gamma, x, out, sw, att_lds, ow_lds);
    } else if (bid < 640) {
        comb_oy_body<N2, 10>(bid - 512, pacc + PAOFF2, pml + PMOFF2,
                             ow + C * INTER, ob + C, gamma + 1, xs2, y2, nullptr,
                             att_lds, ow_lds);
    } else {
        comb_oy_body<N4, 8>(bid - 640, pacc + PAOFF4, pml + PMOFF4,
                            ow + 2 * C * INTER, ob + 2 * C, gamma + 2, xs4, y4, nullptr,
                            att_lds, ow_lds);
    }
}

// ---------- kernel 5: bilinear upsample + weighted fuse ----------
__device__ __forceinline__ float bilerp(const float* __restrict__ img, int in,
                                        int oy, int ox, float r) {
    float cy = (oy + 0.5f) * r - 0.5f;
    cy = fminf(fmaxf(cy, 0.0f), (float)(in - 1));
    float cx = (ox + 0.5f) * r - 0.5f;
    cx = fminf(fmaxf(cx, 0.0f), (float)(in - 1));
    int y0 = (int)cy; int y1i = (y0 + 1 < in) ? y0 + 1 : in - 1; float ty = cy - (float)y0;
    int x0 = (int)cx; int x1i = (x0 + 1 < in) ? x0 + 1 : in - 1; float tx = cx - (float)x0;
    float v00 = img[y0 * in + x0];
    float v01 = img[y0 * in + x1i];
    float v10 = img[y1i * in + x0];
    float v11 = img[y1i * in + x1i];
    float top = v00 * (1.0f - tx) + v01 * tx;
    float bot = v10 * (1.0f - tx) + v11 * tx;
    return top * (1.0f - ty) + bot * ty;
}

__global__ __launch_bounds__(256) void fuse_kernel(float* __restrict__ out,
                                                   const float* __restrict__ y2,
                                                   const float* __restrict__ y4,
                                                   const float* __restrict__ sw) {
    int idx = blockIdx.x * 256 + threadIdx.x;    // B*C*4096
    int p = idx & 4095;
    int bc = idx >> 12;
    int oy = p >> 6, ox = p & 63;
    float w0, w1, w2; scale_wts(sw, w0, w1, w2);
    float v2 = bilerp(y2 + bc * 1024, 32, oy, ox, 0.5f);
    float v4 = bilerp(y4 + bc * 256, 16, oy, ox, 0.25f);
    out[idx] = out[idx] + w1 * v2 + w2 * v4;
}

extern "C" void kernel_launch(void* const* d_in, const int* in_sizes, int n_in,
                              void* d_out, int out_size, void* d_ws, size_t ws_size,
                              hipStream_t stream) {
    const float* x     = (const float*)d_in[0];
    const float* gn_w  = (const float*)d_in[1];
    const float* gn_b  = (const float*)d_in[2];
    const float* qw    = (const float*)d_in[3];
    const float* qb    = (const float*)d_in[4];
    const float* kw    = (const float*)d_in[5];
    const float* kb    = (const float*)d_in[6];
    const float* vw    = (const float*)d_in[7];
    const float* vb    = (const float*)d_in[8];
    const float* ow    = (const float*)d_in[9];
    const float* ob    = (const float*)d_in[10];
    const float* gamma = (const float*)d_in[11];
    const float* sw    = (const float*)d_in[12];
    float* out = (float*)d_out;

    float* ws    = (float*)d_ws;
    float* xs2   = ws;                         // 524288
    float* xs4   = xs2 + 524288;               // 131072
    float* y2    = xs4 + 131072;               // 524288
    float* y4    = y2 + 524288;                // 131072
    float* part  = y4 + 131072;                // 3072
    float* pacc  = part + 3072;                // PATOT
    float* pml   = pacc + PATOT;               // PMTOT
    ushort_t* qbf = (ushort_t*)(pml + PMTOT);  // QTOT ushorts each
    ushort_t* kbf = qbf + QTOT;
    ushort_t* vbf = kbf + QTOT;

    pool_stats_kernel<<<1536, 256, 0, stream>>>(x, xs2, xs4, part);
    qkv_all_kernel<<<1008, 256, 0, stream>>>(x, xs2, xs4, part, gn_w, gn_b,
                                             qw, qb, kw, kb, vw, vb, qbf, kbf, vbf);
    attn_all_kernel<<<1344, 256, 0, stream>>>(qbf, kbf, vbf, pacc, pml);
    comb_oy_all_kernel<<<672, 256, 0, stream>>>(pacc, pml, ow, ob, gamma,
                                                x, xs2, xs4, out, y2, y4, sw);
    fuse_kernel<<<8192, 256, 0, stream>>>(out, y2, y4, sw);
}